// Round 4
// baseline (789.793 us; speedup 1.0000x reference)
//
#include <hip/hip_runtime.h>
#include <hip/hip_bf16.h>
#include <stdint.h>

// ---------- types ----------
typedef __attribute__((ext_vector_type(8))) short short8;   // 8 bf16 in 4 VGPRs
typedef __attribute__((ext_vector_type(4))) float floatx4;  // MFMA accumulator

#define GPTR(p) (const __attribute__((address_space(1))) void*)(p)
#define LPTR(p) (__attribute__((address_space(3))) void*)(p)

__device__ __forceinline__ ushort f2bf(float f) {
    union { float f; uint32_t u; } v; v.f = f;
    uint32_t u = v.u;
    uint32_t r = (u + 0x7FFFu + ((u >> 16) & 1u)) >> 16;   // RNE
    return (ushort)r;
}

// ---------- manual grid barrier (regular launch, graph-capture-safe) ----------
// Sense-reversing barrier in device .bss: NOT in workspace (harness re-poisons
// ws every iteration). Self-restoring across iterations: count ends at 0, gen
// increments monotonically. AGENT-scope acq/rel atomics give cross-XCD
// coherence (G16). Timeout failsafe: break (verify fails) instead of hanging.
__device__ int g_bar_count;
__device__ int g_bar_gen;

__device__ __forceinline__ void grid_sync(int nb) {
    __syncthreads();
    if (threadIdx.x == 0) {
        int g = __hip_atomic_load(&g_bar_gen, __ATOMIC_RELAXED, __HIP_MEMORY_SCOPE_AGENT);
        int prev = __hip_atomic_fetch_add(&g_bar_count, 1, __ATOMIC_ACQ_REL, __HIP_MEMORY_SCOPE_AGENT);
        if (prev == nb - 1) {
            __hip_atomic_store(&g_bar_count, 0, __ATOMIC_RELAXED, __HIP_MEMORY_SCOPE_AGENT);
            __hip_atomic_store(&g_bar_gen, g + 1, __ATOMIC_RELEASE, __HIP_MEMORY_SCOPE_AGENT);
        } else {
            long long t0 = clock64();
            while (__hip_atomic_load(&g_bar_gen, __ATOMIC_ACQUIRE, __HIP_MEMORY_SCOPE_AGENT) == g) {
                __builtin_amdgcn_s_sleep(8);
                if (clock64() - t0 > 100000000LL) break;   // failsafe, never expected
            }
        }
    }
    __syncthreads();
}

// ---------- stage body: weight prep / query-row extract ----------
__device__ __forceinline__ void prep_body(int bx, int by,
                            const float* __restrict__ attn_w, const float* __restrict__ proj_w,
                            const float* __restrict__ x, const int* __restrict__ mask,
                            ushort* __restrict__ wqT, ushort* __restrict__ wk,
                            ushort* __restrict__ wvT, ushort* __restrict__ wpT,
                            ushort* __restrict__ xq) {
    __shared__ float tile[32][33];
    __shared__ int t_sh0;
    const int tid = threadIdx.x;

    if (bx >= 128) {                    // ---- query-row path ----
        int bw = (bx - 128) * 32 + by;
        if (tid < 32) {
            int s = mask[bw * 32 + tid];
            #pragma unroll
            for (int off = 16; off; off >>= 1) s += __shfl_xor(s, off);
            if (tid == 0) t_sh0 = s - 1;
        }
        __syncthreads();
        int t = t_sh0;
        float4 v = ((const float4*)(x + ((size_t)bw * 32 + t) * 1024))[tid];
        ushort4 o;
        o.x = f2bf(v.x); o.y = f2bf(v.y); o.z = f2bf(v.z); o.w = f2bf(v.w);
        ((ushort4*)(xq + (size_t)bw * 1024))[tid] = o;
        __syncthreads();                // protect t_sh0 reuse by next task
        return;
    }

    const int tx = tid & 31, ty = tid >> 5;    // ---- weight path ----
    const int r0 = by * 32;
    if (bx >= 96) {                      // cast: wk[r][c] = attn_w[r][1024+c]
        int c0 = (bx - 96) * 32;
        for (int i = ty; i < 32; i += 8)
            wk[(size_t)(r0 + i) * 1024 + c0 + tx] =
                f2bf(attn_w[(size_t)(r0 + i) * 3072 + 1024 + c0 + tx]);
        return;                          // no LDS touched
    }
    const float* src; ushort* dst; int N, csrc0, c0;
    if (bx < 32)      { src = attn_w; dst = wqT; N = 3072; c0 = bx * 32;        csrc0 = c0; }
    else if (bx < 64) { src = attn_w; dst = wvT; N = 3072; c0 = (bx - 32) * 32; csrc0 = 2048 + c0; }
    else              { src = proj_w; dst = wpT; N = 1024; c0 = (bx - 64) * 32; csrc0 = c0; }
    for (int i = ty; i < 32; i += 8)
        tile[i][tx] = src[(size_t)(r0 + i) * N + csrc0 + tx];
    __syncthreads();
    for (int i = ty; i < 32; i += 8)
        dst[(size_t)(c0 + i) * 1024 + r0 + tx] = f2bf(tile[tx][i]);
    __syncthreads();                     // protect tile reuse by next task
}

// ---------- stage body: 64-tile GEMM, double-buffered LDS ----------
template <bool OUT_BF16, bool ADD_POS>
__device__ __forceinline__ void gemm_body(const ushort* __restrict__ A, int lda, long sA,
                     const ushort* __restrict__ Bt, int ldb, long sB,
                     void* __restrict__ C, int ldc, int cColPerZ, int K,
                     const float* __restrict__ pos, int bm, int bn, int z) {
    __shared__ ushort As[2][64 * 32];
    __shared__ ushort Bs[2][64 * 32];

    A  += (size_t)z * sA;
    Bt += (size_t)z * sB;

    const int tid  = threadIdx.x;
    const int wave = tid >> 6;
    const int lane = tid & 63;
    const int wm = wave & 1, wn = wave >> 1;
    const int quad = lane >> 4, l15 = lane & 15;

    floatx4 acc[2][2] = {};

    const int srow = wave * 16 + (lane >> 2);
    const int kcol = (lane & 3) * 8;
    const ushort* gA = A  + (size_t)(bm * 64 + srow) * lda + kcol;
    const ushort* gB = Bt + (size_t)(bn * 64 + srow) * ldb + kcol;
    const int lofs = wave * 512;        // 16 rows x 32 cols per wave, linear

    __builtin_amdgcn_global_load_lds(GPTR(gA), LPTR(As[0] + lofs), 16, 0, 0);
    __builtin_amdgcn_global_load_lds(GPTR(gB), LPTR(Bs[0] + lofs), 16, 0, 0);
    __syncthreads();

    int cur = 0;
    for (int kt = 0; kt < K; kt += 32) {
        if (kt + 32 < K) {   // prefetch next tile into the other buffer
            __builtin_amdgcn_global_load_lds(GPTR(gA + kt + 32), LPTR(As[cur ^ 1] + lofs), 16, 0, 0);
            __builtin_amdgcn_global_load_lds(GPTR(gB + kt + 32), LPTR(Bs[cur ^ 1] + lofs), 16, 0, 0);
        }
        short8 af[2], bf[2];
        #pragma unroll
        for (int i = 0; i < 2; ++i)
            af[i] = *(const short8*)&As[cur][(wm * 32 + i * 16 + l15) * 32 + quad * 8];
        #pragma unroll
        for (int j = 0; j < 2; ++j)
            bf[j] = *(const short8*)&Bs[cur][(wn * 32 + j * 16 + l15) * 32 + quad * 8];
        #pragma unroll
        for (int i = 0; i < 2; ++i)
            #pragma unroll
            for (int j = 0; j < 2; ++j)
                acc[i][j] = __builtin_amdgcn_mfma_f32_16x16x32_bf16(af[i], bf[j], acc[i][j], 0, 0, 0);
        __syncthreads();                // drains prefetch vmcnt; next tile ready
        cur ^= 1;
    }

    #pragma unroll
    for (int i = 0; i < 2; ++i) {
        #pragma unroll
        for (int j = 0; j < 2; ++j) {
            int r0 = bm * 64 + wm * 32 + i * 16 + quad * 4;
            int cc = z * cColPerZ + bn * 64 + wn * 32 + j * 16 + l15;
            #pragma unroll
            for (int r = 0; r < 4; ++r) {
                float v = acc[i][j][r];
                if (ADD_POS) v += pos[(size_t)((r0 + r) & 255) * 1024 + cc];
                size_t idx = (size_t)(r0 + r) * ldc + cc;
                if (OUT_BF16) ((ushort*)C)[idx] = f2bf(v);
                else          ((float*) C)[idx] = v;
            }
        }
    }
}

// ---------- stage body: U GEMM, direct-register (K=64, no LDS, no barriers) ----------
__device__ __forceinline__ void gemmu_body(const ushort* __restrict__ A, const ushort* __restrict__ Bt,
                  ushort* __restrict__ C, int bm, int bn, int z) {
    const int tid  = threadIdx.x;
    const int wave = tid >> 6;
    const int lane = tid & 63;
    const int wm = wave & 1, wn = wave >> 1;
    const int quad = lane >> 4, l15 = lane & 15;

    const ushort* Ab = A  + (size_t)(bm * 128 + wm * 64 + l15) * 1024 + z * 64 + quad * 8;
    const ushort* Bb = Bt + (size_t)(bn * 128 + wn * 64 + l15) * 1024 + z * 64 + quad * 8;

    short8 af[4][2], bfr[4][2];
    #pragma unroll
    for (int i = 0; i < 4; ++i)
        #pragma unroll
        for (int kk = 0; kk < 2; ++kk) {
            af[i][kk]  = *(const short8*)(Ab + (size_t)(i * 16) * 1024 + kk * 32);
            bfr[i][kk] = *(const short8*)(Bb + (size_t)(i * 16) * 1024 + kk * 32);
        }

    floatx4 acc[4][4] = {};
    #pragma unroll
    for (int kk = 0; kk < 2; ++kk)
        #pragma unroll
        for (int i = 0; i < 4; ++i)
            #pragma unroll
            for (int j = 0; j < 4; ++j)
                acc[i][j] = __builtin_amdgcn_mfma_f32_16x16x32_bf16(af[i][kk], bfr[j][kk], acc[i][j], 0, 0, 0);

    #pragma unroll
    for (int i = 0; i < 4; ++i) {
        #pragma unroll
        for (int j = 0; j < 4; ++j) {
            int r0 = bm * 128 + wm * 64 + i * 16 + quad * 4;
            int c  = bn * 128 + wn * 64 + j * 16 + l15;
            #pragma unroll
            for (int r = 0; r < 4; ++r)
                C[(size_t)(r0 + r) * 16384 + (size_t)z * 1024 + c] = f2bf(acc[i][j][r]);
        }
    }
}

// ---------- stage body: fused scores -> softmax -> Z ----------
__device__ __forceinline__ void attn2_body(const float* __restrict__ x, const int* __restrict__ mask,
                  const ushort* __restrict__ U, ushort* __restrict__ Zo, int bw) {
    __shared__ float  Sp[2][16][16];    // k-half partials
    __shared__ float  Ss[16 * 36];      // scores [h][j]
    __shared__ float  Ps[32 * 16];      // probs [j][h]
    __shared__ int    t_sh;

    const int tid = threadIdx.x;
    const int wave = tid >> 6, lane = tid & 63;
    const int quad = lane >> 4, l15 = lane & 15;

    if (tid < 32) {
        int s = mask[bw * 32 + tid];
        #pragma unroll
        for (int off = 16; off; off >>= 1) s += __shfl_xor(s, off);
        if (tid == 0) t_sh = s - 1;
    }
    __syncthreads();
    const int t = t_sh;

    const int m  = wave & 1;            // m-tile (rows m*16..m*16+15)
    const int kh = wave >> 1;           // k-half (K cols kh*512..kh*512+511)
    const int row = m * 16 + l15;       // x row within window (A fragment row)
    const bool live = (row <= t);

    const float*  xrow = x + ((size_t)bw * 32 + row) * 1024 + kh * 512 + quad * 8;
    const ushort* urow = U + (size_t)bw * 16384 + (size_t)l15 * 1024 + kh * 512 + quad * 8;

    floatx4 acc = {0.f, 0.f, 0.f, 0.f};
    #pragma unroll
    for (int ks = 0; ks < 16; ++ks) {
        short8 a = (short8)0;
        if (live) {
            float4 v0 = *(const float4*)(xrow + ks * 32);
            float4 v1 = *(const float4*)(xrow + ks * 32 + 4);
            a[0] = (short)f2bf(v0.x); a[1] = (short)f2bf(v0.y);
            a[2] = (short)f2bf(v0.z); a[3] = (short)f2bf(v0.w);
            a[4] = (short)f2bf(v1.x); a[5] = (short)f2bf(v1.y);
            a[6] = (short)f2bf(v1.z); a[7] = (short)f2bf(v1.w);
        }
        short8 b = *(const short8*)(urow + ks * 32);
        acc = __builtin_amdgcn_mfma_f32_16x16x32_bf16(a, b, acc, 0, 0, 0);
    }

    // reduce the two k-halves
    if (kh == 1) {
        #pragma unroll
        for (int r = 0; r < 4; ++r) Sp[m][quad * 4 + r][l15] = acc[r];
    }
    __syncthreads();
    if (kh == 0) {
        #pragma unroll
        for (int r = 0; r < 4; ++r)
            Ss[l15 * 36 + m * 16 + quad * 4 + r] =
                (acc[r] + Sp[m][quad * 4 + r][l15]) * 0.125f;
    }
    __syncthreads();

    // softmax per head (wave 0): h = l15, quad owns j = quad*8..quad*8+7
    if (wave == 0) {
        float s[8]; float mx = -1e30f;
        #pragma unroll
        for (int r = 0; r < 8; ++r) {
            int j = quad * 8 + r;
            float v = Ss[l15 * 36 + j];
            v = (j <= t) ? v : -1e30f;
            s[r] = v; mx = fmaxf(mx, v);
        }
        mx = fmaxf(mx, __shfl_xor(mx, 16));
        mx = fmaxf(mx, __shfl_xor(mx, 32));
        float l = 0.f;
        #pragma unroll
        for (int r = 0; r < 8; ++r) { s[r] = __expf(s[r] - mx); l += s[r]; }
        l += __shfl_xor(l, 16);
        l += __shfl_xor(l, 32);
        float inv = 1.f / l;
        #pragma unroll
        for (int r = 0; r < 8; ++r)
            Ps[(quad * 8 + r) * 16 + l15] = s[r] * inv;
    }
    __syncthreads();

    // Z[h][e] = sum_j P[j][h] * x[j][e]; thread owns 4 consecutive e
    const float4* xsrc = (const float4*)(x + (size_t)bw * 32768);
    float zz[16][4];
    #pragma unroll
    for (int h = 0; h < 16; ++h)
        #pragma unroll
        for (int cc = 0; cc < 4; ++cc) zz[h][cc] = 0.f;
    for (int j = 0; j <= t; ++j) {
        float4 p0 = *(const float4*)&Ps[j * 16 + 0];
        float4 p1 = *(const float4*)&Ps[j * 16 + 4];
        float4 p2 = *(const float4*)&Ps[j * 16 + 8];
        float4 p3 = *(const float4*)&Ps[j * 16 + 12];
        float pr[16] = {p0.x, p0.y, p0.z, p0.w, p1.x, p1.y, p1.z, p1.w,
                        p2.x, p2.y, p2.z, p2.w, p3.x, p3.y, p3.z, p3.w};
        float4 xv = xsrc[j * 256 + tid];
        float xf[4] = {xv.x, xv.y, xv.z, xv.w};
        #pragma unroll
        for (int h = 0; h < 16; ++h)
            #pragma unroll
            for (int cc = 0; cc < 4; ++cc)
                zz[h][cc] += pr[h] * xf[cc];
    }
    const int e0 = tid * 4;
    #pragma unroll
    for (int h = 0; h < 16; ++h) {
        ushort4 o;
        o.x = f2bf(zz[h][0]); o.y = f2bf(zz[h][1]);
        o.z = f2bf(zz[h][2]); o.w = f2bf(zz[h][3]);
        *(ushort4*)&Zo[(size_t)bw * 16384 + h * 1024 + e0] = o;
    }
}

// ---------- the megakernel: 6 stages, 5 manual grid syncs, 1 regular dispatch ----------
// grid 512 x 256 = exactly 2 blocks/CU: launch_bounds(256,2) caps VGPR<=256
// (8 waves/CU), static LDS ~27 KB (53.8 KB/CU for 2 blocks). Nothing else runs
// on the device during graph replay, so all 512 blocks are co-resident.
__global__ __launch_bounds__(256, 2)
void mega_kernel(const float* __restrict__ x, const int* __restrict__ mask,
                 const float* __restrict__ pos, const float* __restrict__ attn_w,
                 const float* __restrict__ proj_w, float* __restrict__ out,
                 ushort* __restrict__ U, ushort* __restrict__ Z,
                 ushort* __restrict__ wqT, ushort* __restrict__ wk,
                 ushort* __restrict__ wvT, ushort* __restrict__ wpT,
                 ushort* __restrict__ xq, ushort* __restrict__ q,
                 ushort* __restrict__ y) {
    const int nb = gridDim.x;

    // 1. weight prep + query rows
    for (int task = blockIdx.x; task < 5120; task += nb)
        prep_body(task % 160, task / 160, attn_w, proj_w, x, mask, wqT, wk, wvT, wpT, xq);
    grid_sync(nb);

    // 2. Q = Xq @ Wq  (1024^3), bf16 out
    for (int task = blockIdx.x; task < 256; task += nb)
        gemm_body<true, false>(xq, 1024, 0, wqT, 1024, 0, (void*)q, 1024, 0, 1024,
                               nullptr, task & 15, task >> 4, 0);
    grid_sync(nb);

    // 3. U[bw][h][e] = Q^h @ (Wk^h)^T  — 16 x (1024x1024x64), direct-reg
    for (int task = blockIdx.x; task < 1024; task += nb)
        gemmu_body(q, wk, U, task & 7, (task >> 3) & 7, task >> 6);
    grid_sync(nb);

    // 4. fused scores -> softmax -> Z per window
    for (int task = blockIdx.x; task < 1024; task += nb)
        attn2_body(x, mask, U, Z, task);
    grid_sync(nb);

    // 5. y = Z^h @ Wv^h + pos  — 16 x (1024x64x1024), bf16 out
    for (int task = blockIdx.x; task < 256; task += nb)
        gemm_body<true, true>(Z, 16384, 1024, wvT, 1024, 65536, (void*)y, 1024, 64, 1024,
                              pos, task & 15, 0, task >> 4);
    grid_sync(nb);

    // 6. out = y @ Wproj  (1024^3), f32 out
    for (int task = blockIdx.x; task < 256; task += nb)
        gemm_body<false, false>(y, 1024, 0, wpT, 1024, 0, (void*)out, 1024, 0, 1024,
                                nullptr, task & 15, task >> 4, 0);
}

// ---------- launch ----------
extern "C" void kernel_launch(void* const* d_in, const int* in_sizes, int n_in,
                              void* d_out, int out_size, void* d_ws, size_t ws_size,
                              hipStream_t stream) {
    const float* x        = (const float*)d_in[0];   // (4,256,32,1024)
    const int*   mask     = (const int*)  d_in[1];   // (4,256,32)
    const float* pos_emb  = (const float*)d_in[2];   // (256,1024)
    const float* attn_w   = (const float*)d_in[3];   // (1024,3072)
    const float* proj_w   = (const float*)d_in[4];   // (1024,1024)
    float*       out      = (float*)d_out;           // (1024,1024)

    const long MB2 = 1048576;

    char* ws = (char*)d_ws;
    size_t off = 0;
    ushort* U_bf  = (ushort*)(ws + off); off += (size_t)16 * MB2 * 2;    // U[bw][h][e]
    ushort* Z_bf  = (ushort*)(ws + off); off += (size_t)16 * MB2 * 2;    // Z[bw][h][e]
    ushort* wqT   = (ushort*)(ws + off); off += MB2 * 2;
    ushort* wk    = (ushort*)(ws + off); off += MB2 * 2;
    ushort* wvT   = (ushort*)(ws + off); off += MB2 * 2;
    ushort* wpT   = (ushort*)(ws + off); off += MB2 * 2;
    ushort* xq_bf = (ushort*)(ws + off); off += MB2 * 2;
    ushort* q_bf  = (ushort*)(ws + off); off += MB2 * 2;
    ushort* y_bf  = (ushort*)(ws + off); off += MB2 * 2;

    mega_kernel<<<dim3(512), dim3(256), 0, stream>>>(
        x, mask, pos_emb, attn_w, proj_w, out,
        U_bf, Z_bf, wqT, wk, wvT, wpT, xq_bf, q_bf, y_bf);
}

// Round 5
// 269.462 us; speedup vs baseline: 2.9310x; 2.9310x over previous
//
#include <hip/hip_runtime.h>
#include <hip/hip_bf16.h>
#include <stdint.h>

// ---------- types ----------
typedef __attribute__((ext_vector_type(8))) short short8;   // 8 bf16 in 4 VGPRs
typedef __attribute__((ext_vector_type(4))) float floatx4;  // MFMA accumulator

#define GPTR(p) (const __attribute__((address_space(1))) void*)(p)
#define LPTR(p) (__attribute__((address_space(3))) void*)(p)

__device__ __forceinline__ ushort f2bf(float f) {
    union { float f; uint32_t u; } v; v.f = f;
    uint32_t u = v.u;
    uint32_t r = (u + 0x7FFFu + ((u >> 16) & 1u)) >> 16;   // RNE
    return (ushort)r;
}

// ---------- kernel 1: fused weight prep + query-row extract ----------
// grid (160, 32): bx<128 -> weight transpose/cast tile (bx, by);
//                 bx>=128 -> query row for window bw=(bx-128)*32+by.
__global__ void prep_kernel(const float* __restrict__ attn_w, const float* __restrict__ proj_w,
                            const float* __restrict__ x, const int* __restrict__ mask,
                            ushort* __restrict__ wqT, ushort* __restrict__ wk,
                            ushort* __restrict__ wvT, ushort* __restrict__ wpT,
                            ushort* __restrict__ xq) {
    __shared__ float tile[32][33];
    __shared__ int t_sh;
    const int bx = blockIdx.x, by = blockIdx.y;
    const int tid = threadIdx.x;

    if (bx >= 128) {                    // ---- query-row path ----
        int bw = (bx - 128) * 32 + by;
        if (tid < 32) {
            int s = mask[bw * 32 + tid];
            #pragma unroll
            for (int off = 16; off; off >>= 1) s += __shfl_xor(s, off);
            if (tid == 0) t_sh = s - 1;
        }
        __syncthreads();
        int t = t_sh;
        float4 v = ((const float4*)(x + ((size_t)bw * 32 + t) * 1024))[tid];
        ushort4 o;
        o.x = f2bf(v.x); o.y = f2bf(v.y); o.z = f2bf(v.z); o.w = f2bf(v.w);
        ((ushort4*)(xq + (size_t)bw * 1024))[tid] = o;
        return;
    }

    const int tx = tid & 31, ty = tid >> 5;    // ---- weight path ----
    const int r0 = by * 32;
    if (bx >= 96) {                      // cast: wk[r][c] = attn_w[r][1024+c]
        int c0 = (bx - 96) * 32;
        for (int i = ty; i < 32; i += 8)
            wk[(size_t)(r0 + i) * 1024 + c0 + tx] =
                f2bf(attn_w[(size_t)(r0 + i) * 3072 + 1024 + c0 + tx]);
        return;
    }
    const float* src; ushort* dst; int N, csrc0, c0;
    if (bx < 32)      { src = attn_w; dst = wqT; N = 3072; c0 = bx * 32;        csrc0 = c0; }
    else if (bx < 64) { src = attn_w; dst = wvT; N = 3072; c0 = (bx - 32) * 32; csrc0 = 2048 + c0; }
    else              { src = proj_w; dst = wpT; N = 1024; c0 = (bx - 64) * 32; csrc0 = c0; }
    for (int i = ty; i < 32; i += 8)
        tile[i][tx] = src[(size_t)(r0 + i) * N + csrc0 + tx];
    __syncthreads();
    for (int i = ty; i < 32; i += 8)
        dst[(size_t)(c0 + i) * 1024 + r0 + tx] = f2bf(tile[tx][i]);
}

// ---------- kernel 2: 64-tile GEMM, 8 waves, in-block split-K ----------
// 512 threads: waves 0-3 (kh=0) accumulate K[0,K/2), waves 4-7 K[K/2,K).
// Each half has its own double-buffered 64x32 LDS panels (proven layout /
// bank profile). 16 K-steps instead of 32 -> half the barrier drains;
// 2 waves/SIMD co-hide lgkm/vm latency. Halves reduced via f32 LDS buffer.
template <bool OUT_BF16, bool ADD_POS>
__global__ __launch_bounds__(512)
void gemm64x8_kernel(const ushort* __restrict__ A, int lda, long sA,
                     const ushort* __restrict__ Bt, int ldb, long sB,
                     void* __restrict__ C, int ldc, int cColPerZ, int K,
                     const float* __restrict__ pos) {
    __shared__ ushort As[2][2][64 * 32];   // [dbuf][kh][rows x 32k]
    __shared__ ushort Bs[2][2][64 * 32];
    __shared__ float  Cred[64 * 64];       // kh=1 partial tile

    const int bm = blockIdx.x, bn = blockIdx.y, z = blockIdx.z;
    A  += (size_t)z * sA;
    Bt += (size_t)z * sB;

    const int tid  = threadIdx.x;
    const int w    = tid >> 6;           // 0..7
    const int lane = tid & 63;
    const int kh   = w >> 2;             // K-half
    const int wq   = w & 3;
    const int wm = wq & 1, wn = wq >> 1;
    const int quad = lane >> 4, l15 = lane & 15;

    floatx4 acc[2][2] = {};

    const int KH = K >> 1;
    // staging: wave w stages 16 rows (x 32 k-cols) of A and of B for its half
    const int srow = wq * 16 + (lane >> 2);
    const int scol = kh * KH + (lane & 3) * 8;
    const ushort* gA = A  + (size_t)(bm * 64 + srow) * lda + scol;
    const ushort* gB = Bt + (size_t)(bn * 64 + srow) * ldb + scol;
    const int lofs = wq * 512;           // 16 rows x 32 els

    __builtin_amdgcn_global_load_lds(GPTR(gA), LPTR(As[0][kh] + lofs), 16, 0, 0);
    __builtin_amdgcn_global_load_lds(GPTR(gB), LPTR(Bs[0][kh] + lofs), 16, 0, 0);
    __syncthreads();

    int cur = 0;
    const int NS = KH >> 5;              // K-steps per half (16 for K=1024)
    for (int s = 0; s < NS; ++s) {
        if (s + 1 < NS) {                // prefetch next step into other buffer
            int kt = (s + 1) * 32;
            __builtin_amdgcn_global_load_lds(GPTR(gA + kt), LPTR(As[cur ^ 1][kh] + lofs), 16, 0, 0);
            __builtin_amdgcn_global_load_lds(GPTR(gB + kt), LPTR(Bs[cur ^ 1][kh] + lofs), 16, 0, 0);
        }
        short8 af[2], bf[2];
        #pragma unroll
        for (int i = 0; i < 2; ++i)
            af[i] = *(const short8*)&As[cur][kh][(wm * 32 + i * 16 + l15) * 32 + quad * 8];
        #pragma unroll
        for (int j = 0; j < 2; ++j)
            bf[j] = *(const short8*)&Bs[cur][kh][(wn * 32 + j * 16 + l15) * 32 + quad * 8];
        #pragma unroll
        for (int i = 0; i < 2; ++i)
            #pragma unroll
            for (int j = 0; j < 2; ++j)
                acc[i][j] = __builtin_amdgcn_mfma_f32_16x16x32_bf16(af[i], bf[j], acc[i][j], 0, 0, 0);
        __syncthreads();                 // drains prefetch vmcnt; next step ready
        cur ^= 1;
    }

    // reduce halves: kh=1 waves publish, kh=0 waves add + write out
    if (kh == 1) {
        #pragma unroll
        for (int i = 0; i < 2; ++i)
            #pragma unroll
            for (int j = 0; j < 2; ++j)
                #pragma unroll
                for (int r = 0; r < 4; ++r)
                    Cred[(wm * 32 + i * 16 + quad * 4 + r) * 64 + wn * 32 + j * 16 + l15] =
                        acc[i][j][r];
    }
    __syncthreads();
    if (kh == 0) {
        #pragma unroll
        for (int i = 0; i < 2; ++i) {
            #pragma unroll
            for (int j = 0; j < 2; ++j) {
                int lr = wm * 32 + i * 16 + quad * 4;
                int lc = wn * 32 + j * 16 + l15;
                int r0 = bm * 64 + lr;
                int cc = z * cColPerZ + bn * 64 + lc;
                #pragma unroll
                for (int r = 0; r < 4; ++r) {
                    float v = acc[i][j][r] + Cred[(lr + r) * 64 + lc];
                    if (ADD_POS) v += pos[(size_t)((r0 + r) & 255) * 1024 + cc];
                    size_t idx = (size_t)(r0 + r) * ldc + cc;
                    if (OUT_BF16) ((ushort*)C)[idx] = f2bf(v);
                    else          ((float*) C)[idx] = v;
                }
            }
        }
    }
}

// ---------- kernel 3: U GEMM, direct-register (K=64, no LDS, no barriers) ----------
// U[bw][h][e] = sum_d q[bw, z*64+d] * wk[e, z*64+d];  grid (8,8,16), 128x128 tile.
__global__ __launch_bounds__(256)
void gemmu_kernel(const ushort* __restrict__ A, const ushort* __restrict__ Bt,
                  ushort* __restrict__ C) {
    const int bm = blockIdx.x, bn = blockIdx.y, z = blockIdx.z;
    const int tid  = threadIdx.x;
    const int wave = tid >> 6;
    const int lane = tid & 63;
    const int wm = wave & 1, wn = wave >> 1;
    const int quad = lane >> 4, l15 = lane & 15;

    const ushort* Ab = A  + (size_t)(bm * 128 + wm * 64 + l15) * 1024 + z * 64 + quad * 8;
    const ushort* Bb = Bt + (size_t)(bn * 128 + wn * 64 + l15) * 1024 + z * 64 + quad * 8;

    short8 af[4][2], bfr[4][2];
    #pragma unroll
    for (int i = 0; i < 4; ++i)
        #pragma unroll
        for (int kk = 0; kk < 2; ++kk) {
            af[i][kk]  = *(const short8*)(Ab + (size_t)(i * 16) * 1024 + kk * 32);
            bfr[i][kk] = *(const short8*)(Bb + (size_t)(i * 16) * 1024 + kk * 32);
        }

    floatx4 acc[4][4] = {};
    #pragma unroll
    for (int kk = 0; kk < 2; ++kk)
        #pragma unroll
        for (int i = 0; i < 4; ++i)
            #pragma unroll
            for (int j = 0; j < 4; ++j)
                acc[i][j] = __builtin_amdgcn_mfma_f32_16x16x32_bf16(af[i][kk], bfr[j][kk], acc[i][j], 0, 0, 0);

    #pragma unroll
    for (int i = 0; i < 4; ++i) {
        #pragma unroll
        for (int j = 0; j < 4; ++j) {
            int r0 = bm * 128 + wm * 64 + i * 16 + quad * 4;
            int c  = bn * 128 + wn * 64 + j * 16 + l15;
            #pragma unroll
            for (int r = 0; r < 4; ++r)
                C[(size_t)(r0 + r) * 16384 + (size_t)z * 1024 + c] = f2bf(acc[i][j][r]);
        }
    }
}

// ---------- kernel 4: fused scores -> softmax -> Z, no staging ----------
__global__ __launch_bounds__(256)
void attn2_kernel(const float* __restrict__ x, const int* __restrict__ mask,
                  const ushort* __restrict__ U, ushort* __restrict__ Z) {
    __shared__ float  Sp[2][16][16];    // k-half partials
    __shared__ float  Ss[16 * 36];      // scores [h][j]
    __shared__ float  Ps[32 * 16];      // probs [j][h]
    __shared__ int    t_sh;

    const int bw = blockIdx.x;
    const int tid = threadIdx.x;
    const int wave = tid >> 6, lane = tid & 63;
    const int quad = lane >> 4, l15 = lane & 15;

    if (tid < 32) {
        int s = mask[bw * 32 + tid];
        #pragma unroll
        for (int off = 16; off; off >>= 1) s += __shfl_xor(s, off);
        if (tid == 0) t_sh = s - 1;
    }
    __syncthreads();
    const int t = t_sh;

    const int m  = wave & 1;            // m-tile (rows m*16..m*16+15)
    const int kh = wave >> 1;           // k-half (K cols kh*512..kh*512+511)
    const int row = m * 16 + l15;       // x row within window (A fragment row)
    const bool live = (row <= t);

    const float*  xrow = x + ((size_t)bw * 32 + row) * 1024 + kh * 512 + quad * 8;
    const ushort* urow = U + (size_t)bw * 16384 + (size_t)l15 * 1024 + kh * 512 + quad * 8;

    floatx4 acc = {0.f, 0.f, 0.f, 0.f};
    #pragma unroll
    for (int ks = 0; ks < 16; ++ks) {
        short8 a = (short8)0;
        if (live) {
            float4 v0 = *(const float4*)(xrow + ks * 32);
            float4 v1 = *(const float4*)(xrow + ks * 32 + 4);
            a[0] = (short)f2bf(v0.x); a[1] = (short)f2bf(v0.y);
            a[2] = (short)f2bf(v0.z); a[3] = (short)f2bf(v0.w);
            a[4] = (short)f2bf(v1.x); a[5] = (short)f2bf(v1.y);
            a[6] = (short)f2bf(v1.z); a[7] = (short)f2bf(v1.w);
        }
        short8 b = *(const short8*)(urow + ks * 32);
        acc = __builtin_amdgcn_mfma_f32_16x16x32_bf16(a, b, acc, 0, 0, 0);
    }

    // reduce the two k-halves
    if (kh == 1) {
        #pragma unroll
        for (int r = 0; r < 4; ++r) Sp[m][quad * 4 + r][l15] = acc[r];
    }
    __syncthreads();
    if (kh == 0) {
        #pragma unroll
        for (int r = 0; r < 4; ++r)
            Ss[l15 * 36 + m * 16 + quad * 4 + r] =
                (acc[r] + Sp[m][quad * 4 + r][l15]) * 0.125f;
    }
    __syncthreads();

    // softmax per head (wave 0): h = l15, quad owns j = quad*8..quad*8+7
    if (wave == 0) {
        float s[8]; float mx = -1e30f;
        #pragma unroll
        for (int r = 0; r < 8; ++r) {
            int j = quad * 8 + r;
            float v = Ss[l15 * 36 + j];
            v = (j <= t) ? v : -1e30f;
            s[r] = v; mx = fmaxf(mx, v);
        }
        mx = fmaxf(mx, __shfl_xor(mx, 16));
        mx = fmaxf(mx, __shfl_xor(mx, 32));
        float l = 0.f;
        #pragma unroll
        for (int r = 0; r < 8; ++r) { s[r] = __expf(s[r] - mx); l += s[r]; }
        l += __shfl_xor(l, 16);
        l += __shfl_xor(l, 32);
        float inv = 1.f / l;
        #pragma unroll
        for (int r = 0; r < 8; ++r)
            Ps[(quad * 8 + r) * 16 + l15] = s[r] * inv;
    }
    __syncthreads();

    // Z[h][e] = sum_j P[j][h] * x[j][e]; thread owns 4 consecutive e
    const float4* xsrc = (const float4*)(x + (size_t)bw * 32768);
    float z[16][4];
    #pragma unroll
    for (int h = 0; h < 16; ++h)
        #pragma unroll
        for (int cc = 0; cc < 4; ++cc) z[h][cc] = 0.f;
    for (int j = 0; j <= t; ++j) {
        float4 p0 = *(const float4*)&Ps[j * 16 + 0];
        float4 p1 = *(const float4*)&Ps[j * 16 + 4];
        float4 p2 = *(const float4*)&Ps[j * 16 + 8];
        float4 p3 = *(const float4*)&Ps[j * 16 + 12];
        float pr[16] = {p0.x, p0.y, p0.z, p0.w, p1.x, p1.y, p1.z, p1.w,
                        p2.x, p2.y, p2.z, p2.w, p3.x, p3.y, p3.z, p3.w};
        float4 xv = xsrc[j * 256 + tid];
        float xf[4] = {xv.x, xv.y, xv.z, xv.w};
        #pragma unroll
        for (int h = 0; h < 16; ++h)
            #pragma unroll
            for (int cc = 0; cc < 4; ++cc)
                z[h][cc] += pr[h] * xf[cc];
    }
    const int e0 = tid * 4;
    #pragma unroll
    for (int h = 0; h < 16; ++h) {
        ushort4 o;
        o.x = f2bf(z[h][0]); o.y = f2bf(z[h][1]);
        o.z = f2bf(z[h][2]); o.w = f2bf(z[h][3]);
        *(ushort4*)&Z[(size_t)bw * 16384 + h * 1024 + e0] = o;
    }
}

// ---------- launch ----------
extern "C" void kernel_launch(void* const* d_in, const int* in_sizes, int n_in,
                              void* d_out, int out_size, void* d_ws, size_t ws_size,
                              hipStream_t stream) {
    const float* x        = (const float*)d_in[0];   // (4,256,32,1024)
    const int*   mask     = (const int*)  d_in[1];   // (4,256,32)
    const float* pos_emb  = (const float*)d_in[2];   // (256,1024)
    const float* attn_w   = (const float*)d_in[3];   // (1024,3072)
    const float* proj_w   = (const float*)d_in[4];   // (1024,1024)
    float*       out      = (float*)d_out;           // (1024,1024)

    const long MB2 = 1048576;

    char* ws = (char*)d_ws;
    size_t off = 0;
    ushort* U_bf  = (ushort*)(ws + off); off += (size_t)16 * MB2 * 2;    // U[bw][h][e]
    ushort* Z_bf  = (ushort*)(ws + off); off += (size_t)16 * MB2 * 2;    // Z[bw][h][e]
    ushort* wqT   = (ushort*)(ws + off); off += MB2 * 2;
    ushort* wk    = (ushort*)(ws + off); off += MB2 * 2;
    ushort* wvT   = (ushort*)(ws + off); off += MB2 * 2;
    ushort* wpT   = (ushort*)(ws + off); off += MB2 * 2;
    ushort* xq_bf = (ushort*)(ws + off); off += MB2 * 2;
    ushort* q_bf  = (ushort*)(ws + off); off += MB2 * 2;
    ushort* y_bf  = (ushort*)(ws + off); off += MB2 * 2;

    // 1. weight prep + query rows (one dispatch)
    prep_kernel<<<dim3(160, 32), 256, 0, stream>>>(attn_w, proj_w, x, mask,
                                                   wqT, wk, wvT, wpT, xq_bf);

    // 2. Q = Xq @ Wq  (1024^3), 8-wave split-K, bf16 out
    gemm64x8_kernel<true, false><<<dim3(16, 16, 1), 512, 0, stream>>>(
        xq_bf, 1024, 0, wqT, 1024, 0, (void*)q_bf, 1024, 0, 1024, nullptr);

    // 3. U[bw][h][e] = Q^h @ (Wk^h)^T  — batched 16 x (1024x1024x64), direct-reg
    gemmu_kernel<<<dim3(8, 8, 16), 256, 0, stream>>>(q_bf, wk, U_bf);

    // 4. fused scores -> softmax -> Z per window
    attn2_kernel<<<1024, 256, 0, stream>>>(x, mask, U_bf, Z_bf);

    // 5. y = Z^h @ Wv^h + pos  — batched 16 x (1024x64x1024), bf16 out
    gemm64x8_kernel<true, true><<<dim3(16, 1, 16), 512, 0, stream>>>(
        Z_bf, 16384, 1024, wvT, 1024, 65536, (void*)y_bf, 1024, 64, 1024, pos_emb);

    // 6. out = y @ Wproj  (1024^3), 8-wave split-K, f32 out
    gemm64x8_kernel<false, false><<<dim3(16, 16, 1), 512, 0, stream>>>(
        y_bf, 1024, 0, wpT, 1024, 0, (void*)out, 1024, 0, 1024, nullptr);
}